// Round 2
// baseline (111.681 us; speedup 1.0000x reference)
//
#include <hip/hip_runtime.h>

#define DEV __device__ __forceinline__

typedef __attribute__((ext_vector_type(8))) __bf16 bf16x8;
typedef __attribute__((ext_vector_type(4))) __bf16 bf16x4;
typedef __attribute__((ext_vector_type(4))) float f32x4;
typedef __attribute__((ext_vector_type(4))) float float4v;

typedef __attribute__((address_space(1))) const void ga_void;
typedef __attribute__((address_space(3))) void la_void;

constexpr float ATT_SCALE = 0.125f;  // 1/sqrt(64)

DEV void gload16(const void* g, void* l) {
  __builtin_amdgcn_global_load_lds((ga_void*)g, (la_void*)l, 16, 0, 0);
}

DEV f32x4 mfma_bf16(bf16x8 a, bf16x8 b, f32x4 c) {
  return __builtin_amdgcn_mfma_f32_16x16x32_bf16(a, b, c, 0, 0, 0);
}

// ---------------- cast x (f32 -> bf16), vectorized ----------------
__global__ __launch_bounds__(256) void cast_x_kernel(
    const float* __restrict__ in, __bf16* __restrict__ out, int n4) {
  int i = blockIdx.x * blockDim.x + threadIdx.x;
  int stride = gridDim.x * blockDim.x;
  for (; i < n4; i += stride) {
    float4v v = ((const float4v*)in)[i];
    bf16x4 o;
    o[0] = (__bf16)v[0]; o[1] = (__bf16)v[1];
    o[2] = (__bf16)v[2]; o[3] = (__bf16)v[3];
    ((bf16x4*)out)[i] = o;
  }
}

// ------------- transpose+cast: f32 [K][Nc] -> bf16 [Nc][K] -------------
__global__ __launch_bounds__(256) void transpose_cast_kernel(
    const float* __restrict__ in, __bf16* __restrict__ out, int K, int Nc) {
  __shared__ float tile[32][33];
  int bx = blockIdx.x * 32;  // Nc (col of in)
  int by = blockIdx.y * 32;  // K  (row of in)
  int tx = threadIdx.x, ty = threadIdx.y;
#pragma unroll
  for (int i = ty; i < 32; i += 8)
    tile[i][tx] = in[(size_t)(by + i) * Nc + bx + tx];
  __syncthreads();
#pragma unroll
  for (int i = ty; i < 32; i += 8)
    out[(size_t)(bx + i) * K + by + tx] = (__bf16)tile[tx][i];
}

// ---------------- GEMM1: xb[8192x512] @ wqkvT^T -> split Q/K/Vt ----------------
// m97 structure: 128x128 tile, BK=32, dbuf LDS, global_load_lds w/ pre-swizzled src.
__global__ __launch_bounds__(256) void gemm_qkv_kernel(
    const __bf16* __restrict__ A, const __bf16* __restrict__ Bt,
    const float* __restrict__ bias,
    __bf16* __restrict__ Qo, __bf16* __restrict__ Ko, __bf16* __restrict__ Vto) {
  __shared__ __align__(16) __bf16 As[2][128 * 32];
  __shared__ __align__(16) __bf16 Bs[2][128 * 32];
  const int tid = threadIdx.x;
  const int lane = tid & 63;
  const int w = tid >> 6;
  const int lr = lane & 15, lg = lane >> 4;
  const int m0 = blockIdx.x * 128, n0 = blockIdx.y * 128;
  const int wr = w >> 1, wc = w & 1;

  f32x4 acc[4][4] = {};

  auto stage = [&](int buf, int kt) {
#pragma unroll
    for (int cc = 0; cc < 2; ++cc) {
      int c = w * 2 + cc;
      int row = c * 16 + (lane >> 2);
      int slot = (lane & 3) ^ ((row >> 1) & 3);  // pre-swizzle global source
      gload16(A + (size_t)(m0 + row) * 512 + kt * 32 + slot * 8, &As[buf][c * 512]);
      gload16(Bt + (size_t)(n0 + row) * 512 + kt * 32 + slot * 8, &Bs[buf][c * 512]);
    }
  };

  stage(0, 0);
  __syncthreads();
  for (int kt = 0; kt < 16; ++kt) {
    int cur = kt & 1;
    if (kt < 15) stage(cur ^ 1, kt + 1);
    bf16x8 av[4], bv[4];
#pragma unroll
    for (int i = 0; i < 4; ++i) {
      int row = wr * 64 + i * 16 + lr;
      av[i] = *(const bf16x8*)&As[cur][row * 32 + ((lg ^ ((row >> 1) & 3)) * 8)];
    }
#pragma unroll
    for (int j = 0; j < 4; ++j) {
      int row = wc * 64 + j * 16 + lr;
      bv[j] = *(const bf16x8*)&Bs[cur][row * 32 + ((lg ^ ((row >> 1) & 3)) * 8)];
    }
#pragma unroll
    for (int i = 0; i < 4; ++i)
#pragma unroll
      for (int j = 0; j < 4; ++j)
        acc[i][j] = mfma_bf16(av[i], bv[j], acc[i][j]);
    __syncthreads();
  }

  // epilogue: C layout col=lane&15, row=(lane>>4)*4+reg  [m89]
  const int sec = n0 >> 9;  // 0=Q 1=K 2=V (BN=128 never crosses a 512 boundary)
#pragma unroll
  for (int j = 0; j < 4; ++j) {
    int n = n0 + wc * 64 + j * 16 + lr;
    float bsv = bias[n];
    int nn = n & 511;
    int h = nn >> 6, d = nn & 63;
#pragma unroll
    for (int i = 0; i < 4; ++i) {
#pragma unroll
      for (int r = 0; r < 4; ++r) {
        int m = m0 + wr * 64 + i * 16 + lg * 4 + r;
        int b = m >> 10, nr = m & 1023;
        float v = acc[i][j][r] + bsv;
        if (sec == 0)
          Qo[(((size_t)(b * 8 + h)) * 1024 + nr) * 64 + d] = (__bf16)v;
        else if (sec == 1)
          Ko[(((size_t)(b * 8 + h)) * 1024 + nr) * 64 + d] = (__bf16)v;
        else
          Vto[(((size_t)(b * 8 + h)) * 64 + d) * 1024 + nr] = (__bf16)v;
      }
    }
  }
}

// ---------------- GEMM2: ctx[8192x512] @ woutT^T + b_out -> f32 out ----------------
__global__ __launch_bounds__(256) void gemm_out_kernel(
    const __bf16* __restrict__ A, const __bf16* __restrict__ Bt,
    const float* __restrict__ bias, float* __restrict__ out) {
  __shared__ __align__(16) __bf16 As[2][128 * 32];
  __shared__ __align__(16) __bf16 Bs[2][128 * 32];
  const int tid = threadIdx.x;
  const int lane = tid & 63;
  const int w = tid >> 6;
  const int lr = lane & 15, lg = lane >> 4;
  const int m0 = blockIdx.x * 128, n0 = blockIdx.y * 128;
  const int wr = w >> 1, wc = w & 1;

  f32x4 acc[4][4] = {};

  auto stage = [&](int buf, int kt) {
#pragma unroll
    for (int cc = 0; cc < 2; ++cc) {
      int c = w * 2 + cc;
      int row = c * 16 + (lane >> 2);
      int slot = (lane & 3) ^ ((row >> 1) & 3);
      gload16(A + (size_t)(m0 + row) * 512 + kt * 32 + slot * 8, &As[buf][c * 512]);
      gload16(Bt + (size_t)(n0 + row) * 512 + kt * 32 + slot * 8, &Bs[buf][c * 512]);
    }
  };

  stage(0, 0);
  __syncthreads();
  for (int kt = 0; kt < 16; ++kt) {
    int cur = kt & 1;
    if (kt < 15) stage(cur ^ 1, kt + 1);
    bf16x8 av[4], bv[4];
#pragma unroll
    for (int i = 0; i < 4; ++i) {
      int row = wr * 64 + i * 16 + lr;
      av[i] = *(const bf16x8*)&As[cur][row * 32 + ((lg ^ ((row >> 1) & 3)) * 8)];
    }
#pragma unroll
    for (int j = 0; j < 4; ++j) {
      int row = wc * 64 + j * 16 + lr;
      bv[j] = *(const bf16x8*)&Bs[cur][row * 32 + ((lg ^ ((row >> 1) & 3)) * 8)];
    }
#pragma unroll
    for (int i = 0; i < 4; ++i)
#pragma unroll
      for (int j = 0; j < 4; ++j)
        acc[i][j] = mfma_bf16(av[i], bv[j], acc[i][j]);
    __syncthreads();
  }

#pragma unroll
  for (int j = 0; j < 4; ++j) {
    int n = n0 + wc * 64 + j * 16 + lr;
    float bsv = bias[n];
#pragma unroll
    for (int i = 0; i < 4; ++i) {
#pragma unroll
      for (int r = 0; r < 4; ++r) {
        int m = m0 + wr * 64 + i * 16 + lg * 4 + r;
        out[(size_t)m * 512 + n] = acc[i][j][r] + bsv;
      }
    }
  }
}

// ---------------- flash attention per (b,h), QBLK=64, KBLK=64 ----------------
__global__ __launch_bounds__(256) void attn_kernel(
    const __bf16* __restrict__ Qh, const __bf16* __restrict__ Kh,
    const __bf16* __restrict__ Vth, const float* __restrict__ U,
    const float* __restrict__ mask, __bf16* __restrict__ ctx) {
  __shared__ __align__(16) __bf16 Ks[64 * 64];      // [k][d], swizzled
  __shared__ __align__(16) __bf16 Vs[64 * 64];      // [d][k], swizzled
  __shared__ __align__(16) __bf16 Ps[4][16 * 64];   // per-wave P tile, swizzled
  const int tid = threadIdx.x;
  const int lane = tid & 63;
  const int w = tid >> 6;
  const int lr = lane & 15, lg = lane >> 4;
  const int bh = blockIdx.x, qb = blockIdx.y;
  const int b = bh >> 3, h = bh & 7;

  // Q fragments in registers (A-frag: row = lane&15, k = (lane>>4)*8+j)
  bf16x8 qf[2];
  {
    const __bf16* qp = Qh + ((size_t)bh * 1024 + qb * 64 + w * 16 + lr) * 64;
    qf[0] = *(const bf16x8*)(qp + lg * 8);
    qf[1] = *(const bf16x8*)(qp + 32 + lg * 8);
  }

  f32x4 acc_o[4] = {};
  float m_run[4], l_run[4];
#pragma unroll
  for (int r = 0; r < 4; ++r) { m_run[r] = -3e38f; l_run[r] = 0.f; }

  const int strow = tid >> 2;        // staging row 0..63
  const int stslot = (tid & 3) * 2;  // two 16B slots per thread

  for (int kb = 0; kb < 16; ++kb) {
    __syncthreads();  // prev iter's LDS reads done before overwrite
    {
      const __bf16* kg = Kh + ((size_t)bh * 1024 + kb * 64 + strow) * 64 + stslot * 8;
      bf16x8 k0 = *(const bf16x8*)kg;
      bf16x8 k1 = *(const bf16x8*)(kg + 8);
      const __bf16* vg = Vth + ((size_t)bh * 64 + strow) * 1024 + kb * 64 + stslot * 8;
      bf16x8 v0 = *(const bf16x8*)vg;
      bf16x8 v1 = *(const bf16x8*)(vg + 8);
      int rbase = strow * 64;
      int sw = strow & 7;
      *(bf16x8*)&Ks[rbase + ((stslot ^ sw) * 8)] = k0;
      *(bf16x8*)&Ks[rbase + (((stslot + 1) ^ sw) * 8)] = k1;
      *(bf16x8*)&Vs[rbase + ((stslot ^ sw) * 8)] = v0;
      *(bf16x8*)&Vs[rbase + (((stslot + 1) ^ sw) * 8)] = v1;
    }
    __syncthreads();

    // S = Q K^T  (B-frag: col=lane&15 -> K row t*16+lr)
    f32x4 sv[4];
#pragma unroll
    for (int t = 0; t < 4; ++t) {
      int krow = t * 16 + lr;
      const __bf16* kp = &Ks[krow * 64];
      int sw = krow & 7;
      bf16x8 k0 = *(const bf16x8*)(kp + ((lg ^ sw) * 8));
      bf16x8 k1 = *(const bf16x8*)(kp + (((4 + lg) ^ sw) * 8));
      f32x4 z = {0.f, 0.f, 0.f, 0.f};
      z = mfma_bf16(qf[0], k0, z);
      z = mfma_bf16(qf[1], k1, z);
      sv[t] = z;
    }

    // scale + U + mask (f32)
    float sval[4][4];
    int kc0 = kb * 64;
#pragma unroll
    for (int t = 0; t < 4; ++t) {
      int kcol = kc0 + t * 16 + lr;
      float mk = mask[b * 1024 + kcol];
#pragma unroll
      for (int r = 0; r < 4; ++r) {
        int qrow = qb * 64 + w * 16 + lg * 4 + r;
        sval[t][r] = sv[t][r] * ATT_SCALE + U[(size_t)qrow * 1024 + kcol] + mk;
      }
    }

    // online softmax (row = lg*4+r, spread over 16 lanes of lg-group)
    float pval[4][4];
#pragma unroll
    for (int r = 0; r < 4; ++r) {
      float mx = fmaxf(fmaxf(sval[0][r], sval[1][r]), fmaxf(sval[2][r], sval[3][r]));
      mx = fmaxf(mx, __shfl_xor(mx, 1));
      mx = fmaxf(mx, __shfl_xor(mx, 2));
      mx = fmaxf(mx, __shfl_xor(mx, 4));
      mx = fmaxf(mx, __shfl_xor(mx, 8));
      float mnew = fmaxf(m_run[r], mx);
      float f = __expf(m_run[r] - mnew);
      float ps = 0.f;
#pragma unroll
      for (int t = 0; t < 4; ++t) {
        float p = __expf(sval[t][r] - mnew);
        pval[t][r] = p;
        ps += p;
      }
      ps += __shfl_xor(ps, 1);
      ps += __shfl_xor(ps, 2);
      ps += __shfl_xor(ps, 4);
      ps += __shfl_xor(ps, 8);
      l_run[r] = l_run[r] * f + ps;
      m_run[r] = mnew;
#pragma unroll
      for (int t = 0; t < 4; ++t) acc_o[t][r] *= f;
    }

    // P -> LDS (bf16, swizzled), per-wave region
    {
      __bf16* pw = &Ps[w][0];
#pragma unroll
      for (int t = 0; t < 4; ++t)
#pragma unroll
        for (int r = 0; r < 4; ++r) {
          int q = lg * 4 + r;
          int k = t * 16 + lr;
          pw[q * 64 + (k ^ ((q & 7) << 3))] = (__bf16)pval[t][r];
        }
    }
    __syncthreads();  // cross-lane visibility of P

    // PV: A = P (row=lr), B = V ([kk][d] -> Vs row d = t*16+lr)
    bf16x8 pa0, pa1;
    {
      const __bf16* pp = &Ps[w][lr * 64];
      int sw = lr & 7;
      pa0 = *(const bf16x8*)(pp + ((lg ^ sw) * 8));
      pa1 = *(const bf16x8*)(pp + (((4 + lg) ^ sw) * 8));
    }
#pragma unroll
    for (int t = 0; t < 4; ++t) {
      int vrow = t * 16 + lr;
      const __bf16* vp = &Vs[vrow * 64];
      int sw = vrow & 7;
      bf16x8 v0 = *(const bf16x8*)(vp + ((lg ^ sw) * 8));
      bf16x8 v1 = *(const bf16x8*)(vp + (((4 + lg) ^ sw) * 8));
      acc_o[t] = mfma_bf16(pa0, v0, acc_o[t]);
      acc_o[t] = mfma_bf16(pa1, v1, acc_o[t]);
    }
  }

  // normalize + write ctx (merged heads [B,N,D] bf16)
  float inv[4];
#pragma unroll
  for (int r = 0; r < 4; ++r) inv[r] = 1.0f / l_run[r];
#pragma unroll
  for (int t = 0; t < 4; ++t)
#pragma unroll
    for (int r = 0; r < 4; ++r) {
      int qrow = qb * 64 + w * 16 + lg * 4 + r;
      int d = t * 16 + lr;
      ctx[((size_t)(b * 1024 + qrow)) * 512 + h * 64 + d] = (__bf16)(acc_o[t][r] * inv[r]);
    }
}

extern "C" void kernel_launch(void* const* d_in, const int* in_sizes, int n_in,
                              void* d_out, int out_size, void* d_ws, size_t ws_size,
                              hipStream_t stream) {
  (void)in_sizes; (void)n_in; (void)out_size; (void)ws_size;
  const float* x     = (const float*)d_in[0];
  const float* U     = (const float*)d_in[1];
  const float* mask  = (const float*)d_in[2];
  const float* w_qkv = (const float*)d_in[3];
  const float* b_qkv = (const float*)d_in[4];
  const float* w_out = (const float*)d_in[5];
  const float* b_out = (const float*)d_in[6];
  float* out = (float*)d_out;

  char* p = (char*)d_ws;
  __bf16* xb    = (__bf16*)p; p += (size_t)8192 * 512 * 2;
  __bf16* wqkvT = (__bf16*)p; p += (size_t)1536 * 512 * 2;
  __bf16* woutT = (__bf16*)p; p += (size_t)512 * 512 * 2;
  __bf16* Qh    = (__bf16*)p; p += (size_t)64 * 1024 * 64 * 2;
  __bf16* Kh    = (__bf16*)p; p += (size_t)64 * 1024 * 64 * 2;
  __bf16* Vth   = (__bf16*)p; p += (size_t)64 * 64 * 1024 * 2;
  __bf16* ctx   = (__bf16*)p; p += (size_t)8192 * 512 * 2;

  hipLaunchKernelGGL(cast_x_kernel, dim3(2048), dim3(256), 0, stream,
                     x, xb, 8192 * 512 / 4);
  hipLaunchKernelGGL(transpose_cast_kernel, dim3(48, 16), dim3(32, 8), 0, stream,
                     w_qkv, wqkvT, 512, 1536);
  hipLaunchKernelGGL(transpose_cast_kernel, dim3(16, 16), dim3(32, 8), 0, stream,
                     w_out, woutT, 512, 512);
  hipLaunchKernelGGL(gemm_qkv_kernel, dim3(64, 12), dim3(256), 0, stream,
                     xb, wqkvT, b_qkv, Qh, Kh, Vth);
  hipLaunchKernelGGL(attn_kernel, dim3(64, 16), dim3(256), 0, stream,
                     Qh, Kh, Vth, U, mask, ctx);
  hipLaunchKernelGGL(gemm_out_kernel, dim3(64, 4), dim3(256), 0, stream,
                     ctx, woutT, b_out, out);
}